// Round 9
// baseline (102.381 us; speedup 1.0000x reference)
//
#include <hip/hip_runtime.h>

namespace {

constexpr int THREADS = 512;

struct c32 { float r, i; };

__device__ __forceinline__ c32 cmul(c32 a, c32 b) {
    return { fmaf(a.r, b.r, -(a.i * b.i)), fmaf(a.r, b.i, a.i * b.r) };
}
__device__ __forceinline__ float rfl(float v) {
    return __int_as_float(__builtin_amdgcn_readfirstlane(__float_as_int(v)));
}

// real-coefficient RY butterfly, scalar (SGPR) coefficients: 8 ops/pair
__device__ __forceinline__ void bfy(c32& x, c32& y, float cb, float sb) {
    const c32 a = x, b = y;
    x.r = fmaf(cb, a.r, -(sb * b.r));
    x.i = fmaf(cb, a.i, -(sb * b.i));
    y.r = fmaf(sb, a.r, cb * b.r);
    y.i = fmaf(sb, a.i, cb * b.i);
}
template<int BP>
__device__ __forceinline__ void applyRY8(c32 v[8], float cb, float sb) {
    #pragma unroll
    for (int mi = 0; mi < 4; ++mi) {
        const int i0 = ((mi >> BP) << (BP + 1)) | (mi & ((1 << BP) - 1));
        bfy(v[i0], v[i0 | (1 << BP)], cb, sb);
    }
}

// gamma^k (CNOT-ladder fold) and layout shear Cm2 (GF(2)-linear bank spread)
__host__ __device__ constexpr int Gf(int t, int k) {
    for (int i = 0; i < k; ++i) t = (t ^ (t >> 1)) & 0xFFF;
    return t;
}
__host__ __device__ constexpr int Cm2(int y) {
    const int lo = ((y >> 6) & 1) | (((y >> 7) & 1) << 1) | (((y >> 8) & 1) << 2)
                 | ((((y >> 4) ^ (y >> 6)) & 1) << 3);
    return y ^ lo;
}

// one pass: load 8 amps, apply 3 RY gates (qubits Q0..Q0+2 on reg bits 2..0)
template<int K, int SH, int Q0>
__device__ __forceinline__ void pass_load(const float2* amp, const float4* Vs,
                                          int base, c32 v[8]) {
    const float4 g0 = Vs[(K*12+Q0)*2];
    const float4 g1 = Vs[(K*12+Q0+1)*2];
    const float4 g2 = Vs[(K*12+Q0+2)*2];
    const float cb0 = rfl(g0.x), sb0 = rfl(g0.y);
    const float cb1 = rfl(g1.x), sb1 = rfl(g1.y);
    const float cb2 = rfl(g2.x), sb2 = rfl(g2.y);
    #pragma unroll
    for (int j = 0; j < 8; ++j) {
        const float2 t = amp[base ^ Cm2(Gf(j << SH, K))];
        v[j] = { t.x, t.y };
    }
    applyRY8<2>(v, cb0, sb0);
    applyRY8<1>(v, cb1, sb1);
    applyRY8<0>(v, cb2, sb2);
}

template<int K, int SH>
__device__ __forceinline__ void pass_store(float2* amp, int base, const c32 v[8]) {
    #pragma unroll
    for (int j = 0; j < 8; ++j)
        amp[base ^ Cm2(Gf(j << SH, K))] = make_float2(v[j].r, v[j].i);
    __syncthreads();
}

// one gate layer: 4 passes x 3 qubits; boundary diag at pass D (K<3);
// K==3 fuses the readout and returns the partial expectation value.
template<int K>
__device__ __forceinline__ float doLayer(float2* amp, const float4* Vs,
                                         const float2 (&CAt)[2][32],
                                         const float2 (&CBt)[2][2][16],
                                         const float2 (&Tbt)[2][2][8],
                                         int tid, int eB, int eC) {
    {   // pass A: qubits 0-2 (t bits 11-9)
        const int base = Cm2(Gf(tid, K));
        c32 v[8];
        pass_load<K, 9, 0>(amp, Vs, base, v);
        pass_store<K, 9>(amp, base, v);
    }
    {   // pass B: qubits 3-5 (t bits 8-6)
        const int base = Cm2(Gf(eB, K));
        c32 v[8];
        pass_load<K, 6, 3>(amp, Vs, base, v);
        pass_store<K, 6>(amp, base, v);
    }
    {   // pass C: qubits 6-8 (t bits 5-3)
        const int base = Cm2(Gf(eC, K));
        c32 v[8];
        pass_load<K, 3, 6>(amp, Vs, base, v);
        pass_store<K, 3>(amp, base, v);
    }
    float acc = 0.f;
    {   // pass D: qubits 9-11 (t bits 2-0)
        const int base = Cm2(Gf(tid << 3, K));
        c32 v[8];
        pass_load<K, 0, 9>(amp, Vs, base, v);
        if constexpr (K < 3) {
            const int sgh = __popc(tid >> 4) & 1;
            const int sgt = __popc(tid) & 1;
            const float2 ca  = CAt[K-1][tid >> 4];
            const float2 cbv = CBt[K-1][sgh][tid & 15];
            const c32 W0 = cmul(c32{ca.x, ca.y}, c32{cbv.x, cbv.y});
            #pragma unroll
            for (int j = 0; j < 8; ++j) {
                const float2 tb = Tbt[K-1][sgt][j];
                v[j] = cmul(v[j], cmul(W0, c32{tb.x, tb.y}));
            }
            pass_store<K, 0>(amp, base, v);
        } else {
            // fused readout: t3 = (tid<<3)|j ; weight = parity(t3 & 0x555)
            const int sgn_t = __popc(tid & 0xAA) & 1;
            #pragma unroll
            for (int j = 0; j < 8; ++j) {
                const float m2 = fmaf(v[j].r, v[j].r, v[j].i * v[j].i);
                acc += ((sgn_t ^ __popc(j & 5)) & 1) ? -m2 : m2;
            }
        }
    }
    return acc;
}

__global__ __launch_bounds__(THREADS, 8)
void qcirc_kernel(const float* __restrict__ x, const float* __restrict__ thetas,
                  float* __restrict__ out) {
    __shared__ alignas(16) float2 amp[4096];     // 32 KB state, layout Cm2(G(t,K))
    __shared__ float4 Vs[48 * 2];                // per gate: (cb,sb,p0r,p0i),(p1r,p1i,q1r,q1i)
    __shared__ float2 CAt[2][32];                // boundary diag, t[11:7] part  [K-1][h]
    __shared__ float2 CBt[2][2][16];             // boundary diag, t[6:3] part   [K-1][sgh][lo]
    __shared__ float2 Tbt[2][2][8];              // boundary diag, t[2:0] part   [K-1][sgt][j]

    const int tid = threadIdx.x;
    const int b = blockIdx.x;

    // ---- gate build (threads 0..47): V = RX RZ RX RZfm RYfm ; decompose P*Ry(b)*Q ----
    const float xv = x[b];
    const float x1 = asinf(xv);
    const float x2 = acosf(xv * xv);
    const float cyf = cosf(0.5f * x1), syf = sinf(0.5f * x1);
    const float czf = cosf(0.5f * x2), szf = sinf(0.5f * x2);
    const c32 M00 = {  czf * cyf, -szf * cyf };
    const c32 M01 = { -czf * syf,  szf * syf };
    const c32 M10 = {  czf * syf,  szf * syf };
    const c32 M11 = {  czf * cyf,  szf * cyf };

    if (tid < 48) {
        const float* th = thetas + tid * 3;
        const float h0 = 0.5f * th[0], h1 = 0.5f * th[1], h2 = 0.5f * th[2];
        const float c0 = cosf(h0), s0 = sinf(h0);
        const float c1 = cosf(h1), s1 = sinf(h1);
        const float c2 = cosf(h2), s2 = sinf(h2);
        const c32 z0 = { c1, -s1 }, z1 = { c1, s1 };
        const c32 X00 = { c0, 0.f }, X01 = { 0.f, -s0 };
        const c32 A00 = cmul(z0, X00), A01 = cmul(z0, X01);
        const c32 A10 = cmul(z1, X01), A11 = cmul(z1, X00);
        const c32 Y00 = { c2, 0.f }, Y01 = { 0.f, -s2 };
        const c32 U00 = { Y00.r*A00.r - Y00.i*A00.i + Y01.r*A10.r - Y01.i*A10.i,
                          Y00.r*A00.i + Y00.i*A00.r + Y01.r*A10.i + Y01.i*A10.r };
        const c32 U01 = { Y00.r*A01.r - Y00.i*A01.i + Y01.r*A11.r - Y01.i*A11.i,
                          Y00.r*A01.i + Y00.i*A01.r + Y01.r*A11.i + Y01.i*A11.r };
        const c32 U10 = { Y01.r*A00.r - Y01.i*A00.i + Y00.r*A10.r - Y00.i*A10.i,
                          Y01.r*A00.i + Y01.i*A00.r + Y00.r*A10.i + Y00.i*A10.r };
        const c32 U11 = { Y01.r*A01.r - Y01.i*A01.i + Y00.r*A11.r - Y00.i*A11.i,
                          Y01.r*A01.i + Y01.i*A01.r + Y00.r*A11.i + Y00.i*A11.r };
        const c32 V00 = { U00.r*M00.r - U00.i*M00.i + U01.r*M10.r - U01.i*M10.i,
                          U00.r*M00.i + U00.i*M00.r + U01.r*M10.i + U01.i*M10.r };
        const c32 V01 = { U00.r*M01.r - U00.i*M01.i + U01.r*M11.r - U01.i*M11.i,
                          U00.r*M01.i + U00.i*M01.r + U01.r*M11.i + U01.i*M11.r };
        const c32 V10 = { U10.r*M00.r - U10.i*M00.i + U11.r*M10.r - U11.i*M10.i,
                          U10.r*M00.i + U10.i*M00.r + U11.r*M10.i + U11.i*M10.r };
        const c32 V11 = { U10.r*M01.r - U10.i*M01.i + U11.r*M11.r - U11.i*M11.i,
                          U10.r*M01.i + U10.i*M01.r + U11.r*M11.i + U11.i*M11.r };

        float cb = sqrtf(V00.r*V00.r + V00.i*V00.i);
        float sb = sqrtf(V10.r*V10.r + V10.i*V10.i);
        c32 p0, p1, q1;
        const float eps = 1e-6f;
        if (sb <= eps) {
            const float icb = 1.f / cb;
            p0 = { V00.r*icb, V00.i*icb };
            p1 = { V11.r*icb, V11.i*icb };
            q1 = { 1.f, 0.f };
            cb = 1.f; sb = 0.f;
        } else if (cb <= eps) {
            const float isb = 1.f / sb;
            p1 = { V10.r*isb, V10.i*isb };
            p0 = { -V01.r*isb, -V01.i*isb };
            q1 = { 1.f, 0.f };
            cb = 0.f; sb = 1.f;
        } else {
            const float icb = 1.f / cb, isb = 1.f / sb;
            p0 = { V00.r*icb, V00.i*icb };
            p1 = { V10.r*isb, V10.i*isb };
            const c32 t = { V11.r*p1.r + V11.i*p1.i, V11.i*p1.r - V11.r*p1.i };
            q1 = { t.r*icb, t.i*icb };
        }
        Vs[tid * 2]     = make_float4(cb, sb, p0.r, p0.i);
        Vs[tid * 2 + 1] = make_float4(p1.r, p1.i, q1.r, q1.i);
    }
    __syncthreads();

    // ---- boundary diag tables: B_K = P(K) * (Q(K+1) o gamma^{-1}),  K = 1,2 ----
    if (tid < 64) {                                   // CAt: gates q=0..4, t bits 11..7
        const int bK = 1 + (tid >> 5), h = tid & 31;
        c32 acc = { 1.f, 0.f };
        #pragma unroll
        for (int q = 0; q <= 4; ++q) {
            const float4 s0 = Vs[(bK*12+q)*2], s1 = Vs[(bK*12+q)*2+1];
            const bool bit = (h >> (4 - q)) & 1;
            acc = cmul(acc, c32{ bit ? s1.x : s0.z, bit ? s1.y : s0.w });
            if (__popc(h >> (4 - q)) & 1) {
                const float4 n1 = Vs[((bK+1)*12+q)*2+1];
                acc = cmul(acc, c32{ n1.z, n1.w });
            }
        }
        CAt[bK-1][h] = make_float2(acc.r, acc.i);
    } else if (tid < 128) {                           // CBt: gates q=5..8, t bits 6..3
        const int idx = tid - 64;
        const int bK = 1 + (idx >> 5), sg = (idx >> 4) & 1, lo = idx & 15;
        c32 acc = { 1.f, 0.f };
        #pragma unroll
        for (int q = 5; q <= 8; ++q) {
            const float4 s0 = Vs[(bK*12+q)*2], s1 = Vs[(bK*12+q)*2+1];
            const bool bit = (lo >> (8 - q)) & 1;
            acc = cmul(acc, c32{ bit ? s1.x : s0.z, bit ? s1.y : s0.w });
            if ((sg ^ __popc(lo >> (8 - q))) & 1) {
                const float4 n1 = Vs[((bK+1)*12+q)*2+1];
                acc = cmul(acc, c32{ n1.z, n1.w });
            }
        }
        CBt[bK-1][sg][lo] = make_float2(acc.r, acc.i);
    } else if (tid < 160) {                           // Tbt: gates q=9..11, t bits 2..0
        const int idx = tid - 128;
        const int bK = 1 + (idx >> 4), sg = (idx >> 3) & 1, j = idx & 7;
        c32 acc = { 1.f, 0.f };
        #pragma unroll
        for (int q = 9; q <= 11; ++q) {
            const float4 s0 = Vs[(bK*12+q)*2], s1 = Vs[(bK*12+q)*2+1];
            const bool bit = (j >> (11 - q)) & 1;
            acc = cmul(acc, c32{ bit ? s1.x : s0.z, bit ? s1.y : s0.w });
            if ((sg ^ __popc(j >> (11 - q))) & 1) {
                const float4 n1 = Vs[((bK+1)*12+q)*2+1];
                acc = cmul(acc, c32{ n1.z, n1.w });
            }
        }
        Tbt[bK-1][sg][j] = make_float2(acc.r, acc.i);
    }

    // ---- layer 0: product state (col-0 factors), Q(1) folded; write at Cm2 ----
    {
        const int sgt = __popc(tid) & 1;
        c32 C = { 1.f, 0.f };
        #pragma unroll
        for (int q = 0; q <= 8; ++q) {
            const float4 s0 = Vs[q*2], s1 = Vs[q*2+1];
            const bool bit = (tid >> (8 - q)) & 1;
            C = cmul(C, bit ? c32{ s1.x * s0.y, s1.y * s0.y }
                            : c32{ s0.z * s0.x, s0.w * s0.x });
            if (__popc(tid >> (8 - q)) & 1) {
                const float4 n1 = Vs[(12 + q)*2+1];
                C = cmul(C, c32{ n1.z, n1.w });
            }
        }
        c32 pf0[3], pf1[3], qv[3];
        #pragma unroll
        for (int m = 0; m < 3; ++m) {                 // q = 11-m
            const int q = 11 - m;
            const float4 s0 = Vs[q*2], s1 = Vs[q*2+1];
            const float4 n1 = Vs[(12 + q)*2+1];
            pf0[m] = { s0.z * s0.x, s0.w * s0.x };
            pf1[m] = { s1.x * s0.y, s1.y * s0.y };
            qv[m]  = { n1.z, n1.w };
        }
        const int wbase = Cm2(tid << 3);
        #pragma unroll
        for (int j = 0; j < 8; ++j) {
            c32 T = C;
            #pragma unroll
            for (int m = 2; m >= 0; --m) {
                const bool bit = (j >> m) & 1;
                T = cmul(T, bit ? pf1[m] : pf0[m]);
                if ((sgt ^ __popc(j >> m)) & 1) T = cmul(T, qv[m]);
            }
            amp[wbase ^ j] = make_float2(T.r, T.i);   // Cm2(j)=j for j<16
        }
    }
    __syncthreads();

    // ---- layers 1..3 ----
    const int eB = ((tid >> 6) << 9) | (tid & 63);
    const int eC = ((tid >> 3) << 6) | (tid & 7);
    float acc = 0.f;
    acc += doLayer<1>(amp, Vs, CAt, CBt, Tbt, tid, eB, eC);
    acc += doLayer<2>(amp, Vs, CAt, CBt, Tbt, tid, eB, eC);
    acc += doLayer<3>(amp, Vs, CAt, CBt, Tbt, tid, eB, eC);

    // ---- reduce 512 threads ----
    #pragma unroll
    for (int off = 32; off > 0; off >>= 1) acc += __shfl_down(acc, off, 64);
    __syncthreads();                       // all amp reads done (layer-3 pass D)
    if ((tid & 63) == 0) amp[tid >> 6] = make_float2(acc, 0.f);
    __syncthreads();
    if (tid == 0) {
        float s = 0.f;
        #pragma unroll
        for (int w = 0; w < 8; ++w) s += amp[w].x;
        out[b] = s;
    }
}

} // namespace

extern "C" void kernel_launch(void* const* d_in, const int* in_sizes, int n_in,
                              void* d_out, int out_size, void* d_ws, size_t ws_size,
                              hipStream_t stream) {
    const float* x      = (const float*)d_in[0];
    const float* thetas = (const float*)d_in[1];
    float* out          = (float*)d_out;
    const int batch = in_sizes[0];
    qcirc_kernel<<<batch, THREADS, 0, stream>>>(x, thetas, out);
}

// Round 10
// 92.409 us; speedup vs baseline: 1.1079x; 1.1079x over previous
//
#include <hip/hip_runtime.h>

namespace {

typedef float v2f __attribute__((ext_vector_type(2)));

constexpr int NQ = 12;
constexpr int DIM = 1 << NQ;   // 4096
constexpr int THREADS = 256;

struct c32 { float r, i; };

__device__ __forceinline__ c32 cmul(c32 a, c32 b) {
    return { fmaf(a.r, b.r, -(a.i * b.i)), fmaf(a.r, b.i, a.i * b.r) };
}

// packed RY butterfly: componentwise on (r,i) -> 4 VOP3P ops/pair
__device__ __forceinline__ void bfyp(v2f& x, v2f& y, v2f cb, v2f nsb, v2f sb) {
    const v2f a = x, b2 = y;
    x = __builtin_elementwise_fma(cb, a, nsb * b2);
    y = __builtin_elementwise_fma(sb, a, cb * b2);
}
template<int BP>
__device__ __forceinline__ void applyRYp(v2f v[16], v2f cb, v2f nsb, v2f sb) {
    #pragma unroll
    for (int mi = 0; mi < 8; ++mi) {
        const int i0 = ((mi >> BP) << (BP + 1)) | (mi & ((1 << BP) - 1));
        bfyp(v[i0], v[i0 | (1 << BP)], cb, nsb, sb);
    }
}

// ---- XOR-linear address algebra (identical to passing R5) ----
__host__ __device__ constexpr int G(int t, int k) {
    for (int i = 0; i < k; ++i) t = (t ^ (t >> 1)) & 0xFFF;
    return t;
}
__host__ __device__ constexpr int Cm(int t) {
    int lo = 0;
    if (t & 0x010) lo ^= 0x2;
    if (t & 0x020) lo ^= 0x4;
    if (t & 0x040) lo ^= 0x8;
    if (t & 0x080) lo ^= 0x6;
    if (t & 0x100) lo ^= 0xA;
    if (t & 0x200) lo ^= 0xC;
    return t ^ lo;
}
__host__ __device__ constexpr int maskE_calc() {
    int m = 0;
    for (int i = 0; i < 12; ++i) {
        int v = G(Cm(1 << i), 12), p = 0;
        while (v) { p ^= (v & 1); v >>= 1; }
        if (p) m |= (1 << i);
    }
    return m;
}
constexpr int MASKE = maskE_calc();

// per-thread diag product tree for layer 0 (identical to passing R5)
__device__ __forceinline__ void diagTree(c32 T[16], c32 C,
                                         const c32 pf0[4], const c32 pf1[4],
                                         const c32 qv[4], int sigma) {
    const c32 one = { 1.f, 0.f };
    T[0] = C;
    #pragma unroll
    for (int m = 3; m >= 0; --m) {
        const c32 qs0 = sigma ? qv[m] : one;
        const c32 qs1 = sigma ? one : qv[m];
        const c32 g00 = cmul(pf0[m], qs0);
        const c32 g01 = cmul(pf0[m], qs1);
        const c32 g10 = cmul(pf1[m], qs0);
        const c32 g11 = cmul(pf1[m], qs1);
        #pragma unroll
        for (int e = (1 << (3 - m)) - 1; e >= 0; --e) {
            const int j0 = e << (m + 1);
            const int sfxhi = __popc(e) & 1;
            const c32 ga = sfxhi ? g01 : g00;
            const c32 gb = sfxhi ? g10 : g11;
            T[j0 | (1 << m)] = cmul(T[j0], gb);
            T[j0]            = cmul(T[j0], ga);
        }
    }
}

__global__ __launch_bounds__(THREADS)
void qcirc_kernel(const float* __restrict__ x, const float* __restrict__ thetas,
                  float* __restrict__ out) {
    __shared__ alignas(16) float2 amp[DIM];   // 32 KB state, layout Cm(G(t,l))
    __shared__ float4 Vs[4 * NQ * 2];         // per gate: (cb,sb,p0r,p0i),(p1r,p1i,q1r,q1i)
    __shared__ float2 TbS[2][2][16];          // boundary reg-part tables [K-1][sigma][j]
    __shared__ float2 CHiS[2][16];            // boundary thread-part, high nibble
    __shared__ float2 CLoS[2][2][16];         // boundary thread-part, low nibble
    __shared__ float red[4];
    float4* a4 = reinterpret_cast<float4*>(amp);

    const int tid = threadIdx.x;
    const int b = blockIdx.x;

    // ---- fused gate build + P*Ry(b)*Q decomposition ----
    const float xv = x[b];
    const float x1 = asinf(xv);
    const float x2 = acosf(xv * xv);
    const float cy = cosf(0.5f * x1), sy = sinf(0.5f * x1);
    const float cz = cosf(0.5f * x2), sz = sinf(0.5f * x2);
    const c32 M00 = {  cz * cy, -sz * cy };
    const c32 M01 = { -cz * sy,  sz * sy };
    const c32 M10 = {  cz * sy,  sz * sy };
    const c32 M11 = {  cz * cy,  sz * cy };

    if (tid < 4 * NQ) {
        const float* th = thetas + tid * 3;
        const float h0 = 0.5f * th[0], h1 = 0.5f * th[1], h2 = 0.5f * th[2];
        const float c0 = cosf(h0), s0 = sinf(h0);
        const float c1 = cosf(h1), s1 = sinf(h1);
        const float c2 = cosf(h2), s2 = sinf(h2);
        const c32 z0 = { c1, -s1 }, z1 = { c1, s1 };
        const c32 X00 = { c0, 0.f }, X01 = { 0.f, -s0 };
        const c32 A00 = cmul(z0, X00), A01 = cmul(z0, X01);
        const c32 A10 = cmul(z1, X01), A11 = cmul(z1, X00);
        const c32 Y00 = { c2, 0.f }, Y01 = { 0.f, -s2 };
        const c32 U00 = { Y00.r*A00.r - Y00.i*A00.i + Y01.r*A10.r - Y01.i*A10.i,
                          Y00.r*A00.i + Y00.i*A00.r + Y01.r*A10.i + Y01.i*A10.r };
        const c32 U01 = { Y00.r*A01.r - Y00.i*A01.i + Y01.r*A11.r - Y01.i*A11.i,
                          Y00.r*A01.i + Y00.i*A01.r + Y01.r*A11.i + Y01.i*A11.r };
        const c32 U10 = { Y01.r*A00.r - Y01.i*A00.i + Y00.r*A10.r - Y00.i*A10.i,
                          Y01.r*A00.i + Y01.i*A00.r + Y00.r*A10.i + Y00.i*A10.r };
        const c32 U11 = { Y01.r*A01.r - Y01.i*A01.i + Y00.r*A11.r - Y00.i*A11.i,
                          Y01.r*A01.i + Y01.i*A01.r + Y00.r*A11.i + Y00.i*A11.r };
        const c32 V00 = { U00.r*M00.r - U00.i*M00.i + U01.r*M10.r - U01.i*M10.i,
                          U00.r*M00.i + U00.i*M00.r + U01.r*M10.i + U01.i*M10.r };
        const c32 V01 = { U00.r*M01.r - U00.i*M01.i + U01.r*M11.r - U01.i*M11.i,
                          U00.r*M01.i + U00.i*M01.r + U01.r*M11.i + U01.i*M11.r };
        const c32 V10 = { U10.r*M00.r - U10.i*M00.i + U11.r*M10.r - U11.i*M10.i,
                          U10.r*M00.i + U10.i*M00.r + U11.r*M10.i + U11.i*M10.r };
        const c32 V11 = { U10.r*M01.r - U10.i*M01.i + U11.r*M11.r - U11.i*M11.i,
                          U10.r*M01.i + U10.i*M01.r + U11.r*M11.i + U11.i*M11.r };

        float cb = sqrtf(V00.r*V00.r + V00.i*V00.i);
        float sb = sqrtf(V10.r*V10.r + V10.i*V10.i);
        c32 p0, p1, q1;
        const float eps = 1e-6f;
        if (sb <= eps) {
            const float icb = 1.f / cb;
            p0 = { V00.r*icb, V00.i*icb };
            p1 = { V11.r*icb, V11.i*icb };
            q1 = { 1.f, 0.f };
            cb = 1.f; sb = 0.f;
        } else if (cb <= eps) {
            const float isb = 1.f / sb;
            p1 = { V10.r*isb, V10.i*isb };
            p0 = { -V01.r*isb, -V01.i*isb };
            q1 = { 1.f, 0.f };
            cb = 0.f; sb = 1.f;
        } else {
            const float icb = 1.f / cb, isb = 1.f / sb;
            p0 = { V00.r*icb, V00.i*icb };
            p1 = { V10.r*isb, V10.i*isb };
            const c32 t = { V11.r*p1.r + V11.i*p1.i, V11.i*p1.r - V11.r*p1.i };
            q1 = { t.r*icb, t.i*icb };
        }
        Vs[tid * 2]     = make_float4(cb, sb, p0.r, p0.i);
        Vs[tid * 2 + 1] = make_float4(p1.r, p1.i, q1.r, q1.i);
    }
    __syncthreads();

    // ---- boundary diag tables (K=1,2): B_K = P(K) * (Q(K+1) o gamma^{-1}) ----
    if (tid < 64) {
        const int bK = (tid >> 5) + 1;
        const int sg = (tid >> 4) & 1;
        const int j  = tid & 15;
        c32 acc = { 1.f, 0.f };
        #pragma unroll
        for (int m = 3; m >= 0; --m) {
            const int Q = 11 - m;
            const float4 s0 = Vs[(bK*NQ+Q)*2];
            const float4 s1 = Vs[(bK*NQ+Q)*2+1];
            const float4 n1 = Vs[((bK+1)*NQ+Q)*2+1];
            const c32 pf = ((j >> m) & 1) ? c32{ s1.x, s1.y } : c32{ s0.z, s0.w };
            acc = cmul(acc, pf);
            if (sg ^ (__popc(j >> m) & 1)) acc = cmul(acc, c32{ n1.z, n1.w });
        }
        TbS[bK-1][sg][j] = make_float2(acc.r, acc.i);
    } else if (tid < 96) {
        const int idx = tid - 64;
        const int bK = (idx >> 4) + 1;
        const int h  = idx & 15;
        c32 acc = { 1.f, 0.f };
        #pragma unroll
        for (int Q = 0; Q < 4; ++Q) {
            const float4 s0 = Vs[(bK*NQ+Q)*2];
            const float4 s1 = Vs[(bK*NQ+Q)*2+1];
            const float4 n1 = Vs[((bK+1)*NQ+Q)*2+1];
            const c32 pf = ((h >> (3-Q)) & 1) ? c32{ s1.x, s1.y } : c32{ s0.z, s0.w };
            acc = cmul(acc, pf);
            if (__popc(h >> (3-Q)) & 1) acc = cmul(acc, c32{ n1.z, n1.w });
        }
        CHiS[bK-1][h] = make_float2(acc.r, acc.i);
    } else if (tid < 160) {
        const int idx = tid - 96;
        const int bK = (idx >> 5) + 1;
        const int sh = (idx >> 4) & 1;
        const int lo = idx & 15;
        c32 acc = { 1.f, 0.f };
        #pragma unroll
        for (int Q = 4; Q < 8; ++Q) {
            const float4 s0 = Vs[(bK*NQ+Q)*2];
            const float4 s1 = Vs[(bK*NQ+Q)*2+1];
            const float4 n1 = Vs[((bK+1)*NQ+Q)*2+1];
            const c32 pf = ((lo >> (7-Q)) & 1) ? c32{ s1.x, s1.y } : c32{ s0.z, s0.w };
            acc = cmul(acc, pf);
            if (sh ^ (__popc(lo >> (7-Q)) & 1)) acc = cmul(acc, c32{ n1.z, n1.w });
        }
        CLoS[bK-1][sh][lo] = make_float2(acc.r, acc.i);
    }

    // ---- layer 0: tensor product (col-0 factors) with Q(1) folded in ----
    {
        const int sg0 = __popc(tid) & 1;
        c32 C = { 1.f, 0.f };
        #pragma unroll
        for (int q = 0; q < 8; ++q) {
            const float4 s0 = Vs[q*2];
            const float4 s1 = Vs[q*2+1];
            const bool bit = (tid >> (7 - q)) & 1;
            const c32 e = bit ? c32{ s1.x * s0.y, s1.y * s0.y }
                             : c32{ s0.z * s0.x, s0.w * s0.x };
            C = cmul(C, e);
            const float4 n1 = Vs[(NQ+q)*2+1];
            if (__popc(tid >> (7 - q)) & 1) C = cmul(C, c32{ n1.z, n1.w });
        }
        c32 pf0[4], pf1[4], qv[4];
        #pragma unroll
        for (int m = 0; m < 4; ++m) {
            const int Q = 11 - m;
            const float4 s0 = Vs[Q*2];
            const float4 s1 = Vs[Q*2+1];
            const float4 n1 = Vs[(NQ+Q)*2+1];
            pf0[m] = { s0.z * s0.x, s0.w * s0.x };
            pf1[m] = { s1.x * s0.y, s1.y * s0.y };
            qv[m]  = { n1.z, n1.w };
        }
        c32 T[16];
        diagTree(T, C, pf0, pf1, qv, sg0);
        const int beta = Cm(tid << 4);
        #pragma unroll
        for (int m = 0; m < 8; ++m)
            a4[(beta ^ (2 * m)) >> 1] =
                make_float4(T[2*m].r, T[2*m].i, T[2*m+1].r, T[2*m+1].i);
    }
    __syncthreads();

    // ---- layers 1..3: packed RY passes + boundary diag at pass 2 ----
    const int Lo = tid & 15, Hh = tid >> 4;

    #define GATES4(K, Q0)                                                           \
        const float4 g0 = Vs[((K)*NQ+(Q0))*2],   g1 = Vs[((K)*NQ+(Q0)+1)*2];        \
        const float4 g2 = Vs[((K)*NQ+(Q0)+2)*2], g3 = Vs[((K)*NQ+(Q0)+3)*2];        \
        const v2f cb0 = { g0.x, g0.x }, sb0 = { g0.y, g0.y }, nsb0 = { -g0.y, -g0.y }; \
        const v2f cb1 = { g1.x, g1.x }, sb1 = { g1.y, g1.y }, nsb1 = { -g1.y, -g1.y }; \
        const v2f cb2 = { g2.x, g2.x }, sb2 = { g2.y, g2.y }, nsb2 = { -g2.y, -g2.y }; \
        const v2f cb3 = { g3.x, g3.x }, sb3 = { g3.y, g3.y }, nsb3 = { -g3.y, -g3.y };

    #define RUN_LAYER(K)                                                            \
    {                                                                               \
        /* pass 0: qubits 0-3 (t bits 11-8) */                                      \
        {                                                                           \
            GATES4(K, 0)                                                            \
            const int beta = Cm(G(tid, K));                                         \
            v2f v[16];                                                              \
            _Pragma("unroll")                                                       \
            for (int j = 0; j < 16; ++j) {                                          \
                const float2 t = amp[beta ^ Cm(G(j << 8, K))];                      \
                v[j] = (v2f){ t.x, t.y };                                           \
            }                                                                       \
            applyRYp<3>(v, cb0, nsb0, sb0); applyRYp<2>(v, cb1, nsb1, sb1);         \
            applyRYp<1>(v, cb2, nsb2, sb2); applyRYp<0>(v, cb3, nsb3, sb3);         \
            _Pragma("unroll")                                                       \
            for (int j = 0; j < 16; ++j)                                            \
                amp[beta ^ Cm(G(j << 8, K))] = make_float2(v[j].x, v[j].y);         \
            __syncthreads();                                                        \
        }                                                                           \
        /* pass 1: qubits 4-7 (t bits 7-4) */                                       \
        {                                                                           \
            GATES4(K, 4)                                                            \
            const int beta = Cm(G((Hh << 8) | Lo, K));                              \
            v2f v[16];                                                              \
            _Pragma("unroll")                                                       \
            for (int j = 0; j < 16; ++j) {                                          \
                const float2 t = amp[beta ^ Cm(G(j << 4, K))];                      \
                v[j] = (v2f){ t.x, t.y };                                           \
            }                                                                       \
            applyRYp<3>(v, cb0, nsb0, sb0); applyRYp<2>(v, cb1, nsb1, sb1);         \
            applyRYp<1>(v, cb2, nsb2, sb2); applyRYp<0>(v, cb3, nsb3, sb3);         \
            _Pragma("unroll")                                                       \
            for (int j = 0; j < 16; ++j)                                            \
                amp[beta ^ Cm(G(j << 4, K))] = make_float2(v[j].x, v[j].y);         \
            __syncthreads();                                                        \
        }                                                                           \
        /* pass 2: qubits 8-11 (t bits 3-0), b128; boundary diag before write */    \
        {                                                                           \
            GATES4(K, 8)                                                            \
            const int beta = Cm(G((Hh << 8) | (Lo << 4), K));                       \
            v2f v[16];                                                              \
            _Pragma("unroll")                                                       \
            for (int m = 0; m < 8; ++m) {                                           \
                const int gg = Cm(G(2 * m, K));                                     \
                const float4 F = a4[(beta ^ (gg & ~1)) >> 1];                       \
                const v2f flo = { F.x, F.y }, fhi = { F.z, F.w };                   \
                if (gg & 1) { v[2*m+1] = flo; v[2*m] = fhi; }                       \
                else        { v[2*m] = flo;   v[2*m+1] = fhi; }                     \
            }                                                                       \
            applyRYp<3>(v, cb0, nsb0, sb0); applyRYp<2>(v, cb1, nsb1, sb1);         \
            applyRYp<1>(v, cb2, nsb2, sb2); applyRYp<0>(v, cb3, nsb3, sb3);         \
            if constexpr (K < 3) {                                                  \
                const int sgm = __popc(tid) & 1;                                    \
                const int sgh = __popc(tid >> 4) & 1;                               \
                const float2 ch = CHiS[K-1][Hh];                                    \
                const float2 cl = CLoS[K-1][sgh][Lo];                               \
                const c32 CT = cmul(c32{ch.x,ch.y}, c32{cl.x,cl.y});                \
                _Pragma("unroll")                                                   \
                for (int j = 0; j < 16; ++j) {                                      \
                    const float2 tb = TbS[K-1][sgm][j];                             \
                    const c32 w = cmul(c32{v[j].x, v[j].y}, cmul(CT, c32{tb.x, tb.y})); \
                    v[j] = (v2f){ w.r, w.i };                                       \
                }                                                                   \
            }                                                                       \
            _Pragma("unroll")                                                       \
            for (int m = 0; m < 8; ++m) {                                           \
                const int gg = Cm(G(2 * m, K));                                     \
                float4 F;                                                           \
                if (gg & 1) F = make_float4(v[2*m+1].x, v[2*m+1].y, v[2*m].x,   v[2*m].y); \
                else        F = make_float4(v[2*m].x,   v[2*m].y,   v[2*m+1].x, v[2*m+1].y); \
                a4[(beta ^ (gg & ~1)) >> 1] = F;                                    \
            }                                                                       \
            __syncthreads();                                                        \
        }                                                                           \
    }

    RUN_LAYER(1)
    RUN_LAYER(2)
    RUN_LAYER(3)
    #undef RUN_LAYER
    #undef GATES4

    // ---- readout: weight = parity(MASKE & e); P(3) dropped (pure phase) ----
    float acc = 0.f;
    #pragma unroll
    for (int it = 0; it < 8; ++it) {
        const int pe = (it << 9) | (tid << 1);
        const float4 F = a4[pe >> 1];
        const float m0 = fmaf(F.x, F.x, F.y * F.y);
        const float m1 = fmaf(F.z, F.z, F.w * F.w);
        acc += (__popc(pe & MASKE) & 1) ? -m0 : m0;
        acc += (__popc((pe | 1) & MASKE) & 1) ? -m1 : m1;
    }
    #pragma unroll
    for (int off = 32; off > 0; off >>= 1) acc += __shfl_down(acc, off, 64);
    if ((tid & 63) == 0) red[tid >> 6] = acc;
    __syncthreads();
    if (tid == 0) out[b] = red[0] + red[1] + red[2] + red[3];
}

} // namespace

extern "C" void kernel_launch(void* const* d_in, const int* in_sizes, int n_in,
                              void* d_out, int out_size, void* d_ws, size_t ws_size,
                              hipStream_t stream) {
    const float* x      = (const float*)d_in[0];
    const float* thetas = (const float*)d_in[1];
    float* out          = (float*)d_out;
    const int batch = in_sizes[0];
    qcirc_kernel<<<batch, THREADS, 0, stream>>>(x, thetas, out);
}

// Round 11
// 90.748 us; speedup vs baseline: 1.1282x; 1.0183x over previous
//
#include <hip/hip_runtime.h>

namespace {

constexpr int NQ = 12;
constexpr int DIM = 1 << NQ;   // 4096
constexpr int THREADS = 256;

struct c32 { float r, i; };

__device__ __forceinline__ c32 cmul(c32 a, c32 b) {
    return { fmaf(a.r, b.r, -(a.i * b.i)), fmaf(a.r, b.i, a.i * b.r) };
}

// real-coefficient RY butterfly: (x,y) <- (cb*x - sb*y, sb*x + cb*y), 8 ops/pair
__device__ __forceinline__ void bfy(c32& x, c32& y, float cb, float sb) {
    const c32 a = x, b = y;
    x.r = fmaf(cb, a.r, -(sb * b.r));
    x.i = fmaf(cb, a.i, -(sb * b.i));
    y.r = fmaf(sb, a.r, cb * b.r);
    y.i = fmaf(sb, a.i, cb * b.i);
}

template<int BP>
__device__ __forceinline__ void applyRY(c32 v[16], float cb, float sb) {
    #pragma unroll
    for (int mi = 0; mi < 8; ++mi) {
        const int i0 = ((mi >> BP) << (BP + 1)) | (mi & ((1 << BP) - 1));
        bfy(v[i0], v[i0 | (1 << BP)], cb, sb);
    }
}

// ---- XOR-linear address algebra (identical to the 90.6us R5 kernel) ----
__host__ __device__ constexpr int G(int t, int k) {
    for (int i = 0; i < k; ++i) t = (t ^ (t >> 1)) & 0xFFF;
    return t;
}
__host__ __device__ constexpr int Cm(int t) {
    int lo = 0;
    if (t & 0x010) lo ^= 0x2;
    if (t & 0x020) lo ^= 0x4;
    if (t & 0x040) lo ^= 0x8;
    if (t & 0x080) lo ^= 0x6;
    if (t & 0x100) lo ^= 0xA;
    if (t & 0x200) lo ^= 0xC;
    return t ^ lo;
}

// per-thread diag product tree for layer 0 (identical to R5)
__device__ __forceinline__ void diagTree(c32 T[16], c32 C,
                                         const c32 pf0[4], const c32 pf1[4],
                                         const c32 qv[4], int sigma) {
    const c32 one = { 1.f, 0.f };
    T[0] = C;
    #pragma unroll
    for (int m = 3; m >= 0; --m) {
        const c32 qs0 = sigma ? qv[m] : one;
        const c32 qs1 = sigma ? one : qv[m];
        const c32 g00 = cmul(pf0[m], qs0);
        const c32 g01 = cmul(pf0[m], qs1);
        const c32 g10 = cmul(pf1[m], qs0);
        const c32 g11 = cmul(pf1[m], qs1);
        #pragma unroll
        for (int e = (1 << (3 - m)) - 1; e >= 0; --e) {
            const int j0 = e << (m + 1);
            const int sfxhi = __popc(e) & 1;
            const c32 ga = sfxhi ? g01 : g00;
            const c32 gb = sfxhi ? g10 : g11;
            T[j0 | (1 << m)] = cmul(T[j0], gb);
            T[j0]            = cmul(T[j0], ga);
        }
    }
}

__global__ __launch_bounds__(THREADS)
void qcirc_kernel(const float* __restrict__ x, const float* __restrict__ thetas,
                  float* __restrict__ out) {
    __shared__ alignas(16) float2 amp[DIM];   // 32 KB state, layout Cm(G(t,l))
    __shared__ float4 Vs[4 * NQ * 2];         // per gate: (cb,sb,p0r,p0i),(p1r,p1i,q1r,q1i)
    __shared__ float2 TbS[2][2][16];          // boundary reg-part tables [K-1][sigma][j]
    __shared__ float2 CHiS[2][16];            // boundary thread-part, high nibble
    __shared__ float2 CLoS[2][2][16];         // boundary thread-part, low nibble
    __shared__ float red[4];
    float4* a4 = reinterpret_cast<float4*>(amp);

    const int tid = threadIdx.x;
    const int b = blockIdx.x;

    // ---- fused gate build + P*Ry(b)*Q decomposition ----
    const float xv = x[b];
    const float x1 = asinf(xv);
    const float x2 = acosf(xv * xv);
    const float cy = cosf(0.5f * x1), sy = sinf(0.5f * x1);
    const float cz = cosf(0.5f * x2), sz = sinf(0.5f * x2);
    const c32 M00 = {  cz * cy, -sz * cy };
    const c32 M01 = { -cz * sy,  sz * sy };
    const c32 M10 = {  cz * sy,  sz * sy };
    const c32 M11 = {  cz * cy,  sz * cy };

    if (tid < 4 * NQ) {
        const float* th = thetas + tid * 3;
        const float h0 = 0.5f * th[0], h1 = 0.5f * th[1], h2 = 0.5f * th[2];
        const float c0 = cosf(h0), s0 = sinf(h0);
        const float c1 = cosf(h1), s1 = sinf(h1);
        const float c2 = cosf(h2), s2 = sinf(h2);
        const c32 z0 = { c1, -s1 }, z1 = { c1, s1 };
        const c32 X00 = { c0, 0.f }, X01 = { 0.f, -s0 };
        const c32 A00 = cmul(z0, X00), A01 = cmul(z0, X01);
        const c32 A10 = cmul(z1, X01), A11 = cmul(z1, X00);
        const c32 Y00 = { c2, 0.f }, Y01 = { 0.f, -s2 };
        const c32 U00 = { Y00.r*A00.r - Y00.i*A00.i + Y01.r*A10.r - Y01.i*A10.i,
                          Y00.r*A00.i + Y00.i*A00.r + Y01.r*A10.i + Y01.i*A10.r };
        const c32 U01 = { Y00.r*A01.r - Y00.i*A01.i + Y01.r*A11.r - Y01.i*A11.i,
                          Y00.r*A01.i + Y00.i*A01.r + Y01.r*A11.i + Y01.i*A11.r };
        const c32 U10 = { Y01.r*A00.r - Y01.i*A00.i + Y00.r*A10.r - Y00.i*A10.i,
                          Y01.r*A00.i + Y01.i*A00.r + Y00.r*A10.i + Y00.i*A10.r };
        const c32 U11 = { Y01.r*A01.r - Y01.i*A01.i + Y00.r*A11.r - Y00.i*A11.i,
                          Y01.r*A01.i + Y01.i*A01.r + Y00.r*A11.i + Y00.i*A11.r };
        const c32 V00 = { U00.r*M00.r - U00.i*M00.i + U01.r*M10.r - U01.i*M10.i,
                          U00.r*M00.i + U00.i*M00.r + U01.r*M10.i + U01.i*M10.r };
        const c32 V01 = { U00.r*M01.r - U00.i*M01.i + U01.r*M11.r - U01.i*M11.i,
                          U00.r*M01.i + U00.i*M01.r + U01.r*M11.i + U01.i*M11.r };
        const c32 V10 = { U10.r*M00.r - U10.i*M00.i + U11.r*M10.r - U11.i*M10.i,
                          U10.r*M00.i + U10.i*M00.r + U11.r*M10.i + U11.i*M10.r };
        const c32 V11 = { U10.r*M01.r - U10.i*M01.i + U11.r*M11.r - U11.i*M11.i,
                          U10.r*M01.i + U10.i*M01.r + U11.r*M11.i + U11.i*M11.r };

        float cb = sqrtf(V00.r*V00.r + V00.i*V00.i);
        float sb = sqrtf(V10.r*V10.r + V10.i*V10.i);
        c32 p0, p1, q1;
        const float eps = 1e-6f;
        if (sb <= eps) {
            const float icb = 1.f / cb;
            p0 = { V00.r*icb, V00.i*icb };
            p1 = { V11.r*icb, V11.i*icb };
            q1 = { 1.f, 0.f };
            cb = 1.f; sb = 0.f;
        } else if (cb <= eps) {
            const float isb = 1.f / sb;
            p1 = { V10.r*isb, V10.i*isb };
            p0 = { -V01.r*isb, -V01.i*isb };
            q1 = { 1.f, 0.f };
            cb = 0.f; sb = 1.f;
        } else {
            const float icb = 1.f / cb, isb = 1.f / sb;
            p0 = { V00.r*icb, V00.i*icb };
            p1 = { V10.r*isb, V10.i*isb };
            const c32 t = { V11.r*p1.r + V11.i*p1.i, V11.i*p1.r - V11.r*p1.i };
            q1 = { t.r*icb, t.i*icb };
        }
        Vs[tid * 2]     = make_float4(cb, sb, p0.r, p0.i);
        Vs[tid * 2 + 1] = make_float4(p1.r, p1.i, q1.r, q1.i);
    }
    __syncthreads();

    // ---- boundary diag tables (K=1,2): B_K = P(K) * (Q(K+1) o gamma^{-1}) ----
    if (tid < 64) {
        const int bK = (tid >> 5) + 1;
        const int sg = (tid >> 4) & 1;
        const int j  = tid & 15;
        c32 acc = { 1.f, 0.f };
        #pragma unroll
        for (int m = 3; m >= 0; --m) {
            const int Q = 11 - m;
            const float4 s0 = Vs[(bK*NQ+Q)*2];
            const float4 s1 = Vs[(bK*NQ+Q)*2+1];
            const float4 n1 = Vs[((bK+1)*NQ+Q)*2+1];
            const c32 pf = ((j >> m) & 1) ? c32{ s1.x, s1.y } : c32{ s0.z, s0.w };
            acc = cmul(acc, pf);
            if (sg ^ (__popc(j >> m) & 1)) acc = cmul(acc, c32{ n1.z, n1.w });
        }
        TbS[bK-1][sg][j] = make_float2(acc.r, acc.i);
    } else if (tid < 96) {
        const int idx = tid - 64;
        const int bK = (idx >> 4) + 1;
        const int h  = idx & 15;
        c32 acc = { 1.f, 0.f };
        #pragma unroll
        for (int Q = 0; Q < 4; ++Q) {
            const float4 s0 = Vs[(bK*NQ+Q)*2];
            const float4 s1 = Vs[(bK*NQ+Q)*2+1];
            const float4 n1 = Vs[((bK+1)*NQ+Q)*2+1];
            const c32 pf = ((h >> (3-Q)) & 1) ? c32{ s1.x, s1.y } : c32{ s0.z, s0.w };
            acc = cmul(acc, pf);
            if (__popc(h >> (3-Q)) & 1) acc = cmul(acc, c32{ n1.z, n1.w });
        }
        CHiS[bK-1][h] = make_float2(acc.r, acc.i);
    } else if (tid < 160) {
        const int idx = tid - 96;
        const int bK = (idx >> 5) + 1;
        const int sh = (idx >> 4) & 1;
        const int lo = idx & 15;
        c32 acc = { 1.f, 0.f };
        #pragma unroll
        for (int Q = 4; Q < 8; ++Q) {
            const float4 s0 = Vs[(bK*NQ+Q)*2];
            const float4 s1 = Vs[(bK*NQ+Q)*2+1];
            const float4 n1 = Vs[((bK+1)*NQ+Q)*2+1];
            const c32 pf = ((lo >> (7-Q)) & 1) ? c32{ s1.x, s1.y } : c32{ s0.z, s0.w };
            acc = cmul(acc, pf);
            if (sh ^ (__popc(lo >> (7-Q)) & 1)) acc = cmul(acc, c32{ n1.z, n1.w });
        }
        CLoS[bK-1][sh][lo] = make_float2(acc.r, acc.i);
    }

    // ---- layer 0: tensor product (col-0 factors) with Q(1) folded in ----
    {
        const int sg0 = __popc(tid) & 1;
        c32 C = { 1.f, 0.f };
        #pragma unroll
        for (int q = 0; q < 8; ++q) {
            const float4 s0 = Vs[q*2];
            const float4 s1 = Vs[q*2+1];
            const bool bit = (tid >> (7 - q)) & 1;
            const c32 e = bit ? c32{ s1.x * s0.y, s1.y * s0.y }
                             : c32{ s0.z * s0.x, s0.w * s0.x };
            C = cmul(C, e);
            const float4 n1 = Vs[(NQ+q)*2+1];
            if (__popc(tid >> (7 - q)) & 1) C = cmul(C, c32{ n1.z, n1.w });
        }
        c32 pf0[4], pf1[4], qv[4];
        #pragma unroll
        for (int m = 0; m < 4; ++m) {
            const int Q = 11 - m;
            const float4 s0 = Vs[Q*2];
            const float4 s1 = Vs[Q*2+1];
            const float4 n1 = Vs[(NQ+Q)*2+1];
            pf0[m] = { s0.z * s0.x, s0.w * s0.x };
            pf1[m] = { s1.x * s0.y, s1.y * s0.y };
            qv[m]  = { n1.z, n1.w };
        }
        c32 T[16];
        diagTree(T, C, pf0, pf1, qv, sg0);
        const int beta = Cm(tid << 4);
        #pragma unroll
        for (int m = 0; m < 8; ++m)
            a4[(beta ^ (2 * m)) >> 1] =
                make_float4(T[2*m].r, T[2*m].i, T[2*m+1].r, T[2*m+1].i);
    }
    __syncthreads();

    // ---- layers 1..3: RY passes + boundary diag at pass 2; layer-3 pass 2
    //      fuses the readout (weight = parity(t & 0x555), ladder #4 folded) ----
    const int Lo = tid & 15, Hh = tid >> 4;
    float acc = 0.f;

    #define RUN_LAYER(K)                                                            \
    {                                                                               \
        /* pass 0: qubits 0-3 (t bits 11-8) */                                      \
        {                                                                           \
            const float4 g0 = Vs[(K*NQ+0)*2], g1 = Vs[(K*NQ+1)*2];                  \
            const float4 g2 = Vs[(K*NQ+2)*2], g3 = Vs[(K*NQ+3)*2];                  \
            const int beta = Cm(G(tid, K));                                         \
            c32 v[16];                                                              \
            _Pragma("unroll")                                                       \
            for (int j = 0; j < 16; ++j) {                                          \
                const float2 t = amp[beta ^ Cm(G(j << 8, K))];                      \
                v[j] = { t.x, t.y };                                                \
            }                                                                       \
            applyRY<3>(v, g0.x, g0.y); applyRY<2>(v, g1.x, g1.y);                   \
            applyRY<1>(v, g2.x, g2.y); applyRY<0>(v, g3.x, g3.y);                   \
            _Pragma("unroll")                                                       \
            for (int j = 0; j < 16; ++j)                                            \
                amp[beta ^ Cm(G(j << 8, K))] = make_float2(v[j].r, v[j].i);         \
            __syncthreads();                                                        \
        }                                                                           \
        /* pass 1: qubits 4-7 (t bits 7-4) */                                       \
        {                                                                           \
            const float4 g0 = Vs[(K*NQ+4)*2], g1 = Vs[(K*NQ+5)*2];                  \
            const float4 g2 = Vs[(K*NQ+6)*2], g3 = Vs[(K*NQ+7)*2];                  \
            const int beta = Cm(G((Hh << 8) | Lo, K));                              \
            c32 v[16];                                                              \
            _Pragma("unroll")                                                       \
            for (int j = 0; j < 16; ++j) {                                          \
                const float2 t = amp[beta ^ Cm(G(j << 4, K))];                      \
                v[j] = { t.x, t.y };                                                \
            }                                                                       \
            applyRY<3>(v, g0.x, g0.y); applyRY<2>(v, g1.x, g1.y);                   \
            applyRY<1>(v, g2.x, g2.y); applyRY<0>(v, g3.x, g3.y);                   \
            _Pragma("unroll")                                                       \
            for (int j = 0; j < 16; ++j)                                            \
                amp[beta ^ Cm(G(j << 4, K))] = make_float2(v[j].r, v[j].i);         \
            __syncthreads();                                                        \
        }                                                                           \
        /* pass 2: qubits 8-11 (t bits 3-0), b128 reads */                          \
        {                                                                           \
            const float4 g0 = Vs[(K*NQ+8)*2],  g1 = Vs[(K*NQ+9)*2];                 \
            const float4 g2 = Vs[(K*NQ+10)*2], g3 = Vs[(K*NQ+11)*2];                \
            const int beta = Cm(G((Hh << 8) | (Lo << 4), K));                       \
            c32 v[16];                                                              \
            _Pragma("unroll")                                                       \
            for (int m = 0; m < 8; ++m) {                                           \
                const int gg = Cm(G(2 * m, K));                                     \
                const float4 F = a4[(beta ^ (gg & ~1)) >> 1];                       \
                const c32 flo = { F.x, F.y }, fhi = { F.z, F.w };                   \
                if (gg & 1) { v[2*m+1] = flo; v[2*m] = fhi; }                       \
                else        { v[2*m] = flo;   v[2*m+1] = fhi; }                     \
            }                                                                       \
            applyRY<3>(v, g0.x, g0.y); applyRY<2>(v, g1.x, g1.y);                   \
            applyRY<1>(v, g2.x, g2.y); applyRY<0>(v, g3.x, g3.y);                   \
            if constexpr (K < 3) {                                                  \
                const int sgm = __popc(tid) & 1;                                    \
                const int sgh = __popc(tid >> 4) & 1;                               \
                const float2 ch = CHiS[K-1][Hh];                                    \
                const float2 cl = CLoS[K-1][sgh][Lo];                               \
                const c32 CT = cmul(c32{ch.x,ch.y}, c32{cl.x,cl.y});                \
                _Pragma("unroll")                                                   \
                for (int j = 0; j < 16; ++j) {                                      \
                    const float2 tb = TbS[K-1][sgm][j];                             \
                    v[j] = cmul(v[j], cmul(CT, c32{tb.x, tb.y}));                   \
                }                                                                   \
                _Pragma("unroll")                                                   \
                for (int m = 0; m < 8; ++m) {                                       \
                    const int gg = Cm(G(2 * m, K));                                 \
                    float4 F;                                                       \
                    if (gg & 1) F = make_float4(v[2*m+1].r, v[2*m+1].i, v[2*m].r,   v[2*m].i); \
                    else        F = make_float4(v[2*m].r,   v[2*m].i,   v[2*m+1].r, v[2*m+1].i); \
                    a4[(beta ^ (gg & ~1)) >> 1] = F;                                \
                }                                                                   \
                __syncthreads();                                                    \
            } else {                                                                \
                /* fused readout: t = (Hh<<8)|(Lo<<4)|j, weight = parity(t&0x555) */ \
                const int sgnHL = (__popc(Hh & 5) ^ __popc(Lo & 5)) & 1;            \
                _Pragma("unroll")                                                   \
                for (int j = 0; j < 16; ++j) {                                      \
                    const float m2 = fmaf(v[j].r, v[j].r, v[j].i * v[j].i);         \
                    acc += ((sgnHL ^ __popc(j & 5)) & 1) ? -m2 : m2;                \
                }                                                                   \
            }                                                                       \
        }                                                                           \
    }

    RUN_LAYER(1)
    RUN_LAYER(2)
    RUN_LAYER(3)
    #undef RUN_LAYER

    // ---- reduce 256 threads ----
    #pragma unroll
    for (int off = 32; off > 0; off >>= 1) acc += __shfl_down(acc, off, 64);
    if ((tid & 63) == 0) red[tid >> 6] = acc;
    __syncthreads();
    if (tid == 0) out[b] = red[0] + red[1] + red[2] + red[3];
}

} // namespace

extern "C" void kernel_launch(void* const* d_in, const int* in_sizes, int n_in,
                              void* d_out, int out_size, void* d_ws, size_t ws_size,
                              hipStream_t stream) {
    const float* x      = (const float*)d_in[0];
    const float* thetas = (const float*)d_in[1];
    float* out          = (float*)d_out;
    const int batch = in_sizes[0];
    qcirc_kernel<<<batch, THREADS, 0, stream>>>(x, thetas, out);
}